// Round 1
// baseline (6990.329 us; speedup 1.0000x reference)
//
#include <hip/hip_runtime.h>
#include <math.h>

#define B 64
#define P 196
#define E 2048
#define D 256
#define H_ 256
#define EM 256
#define V 10000
#define L 32
#define T 31

// ---------------- sort: stable argsort descending by length ----------------
__global__ __launch_bounds__(64) void sort_kernel(const int* __restrict__ clen,
                                                  int* __restrict__ order,
                                                  int* __restrict__ target) {
    __shared__ int len_s[B];
    int i = threadIdx.x;
    len_s[i] = clen[i];
    __syncthreads();
    int li = len_s[i];
    int rank = 0;
    for (int j = 0; j < B; ++j) {
        int lj = len_s[j];
        if (lj > li || (lj == li && j < i)) rank++;
    }
    order[rank] = i;
    target[rank] = li - 1;
}

// ---------------- mean_feat[b][e] = mean_p feat[src][p][e] ----------------
__global__ __launch_bounds__(256) void mean_kernel(const float* __restrict__ feat,
                                                   const int* __restrict__ order,
                                                   float* __restrict__ mean_feat) {
    int b = blockIdx.x;
    int e = blockIdx.y * 256 + threadIdx.x;
    int src = order[b];
    const float* fp = feat + (size_t)src * P * E + e;
    float acc = 0.f;
    #pragma unroll 4
    for (int p = 0; p < P; ++p) acc += fp[(size_t)p * E];
    mean_feat[b * E + e] = acc * (1.0f / (float)P);
}

// ---------------- h0 = mean@W_hid+b, c0 = mean@W_cell+b ----------------
__global__ __launch_bounds__(256) void h0c0_kernel(const float* __restrict__ mean_feat,
                                                   const float* __restrict__ W_hid,
                                                   const float* __restrict__ b_hid,
                                                   const float* __restrict__ W_cell,
                                                   const float* __restrict__ b_cell,
                                                   float* __restrict__ h,
                                                   float* __restrict__ c) {
    __shared__ float mf[E];
    int b = blockIdx.x;
    for (int i = threadIdx.x; i < E; i += 256) mf[i] = mean_feat[b * E + i];
    __syncthreads();
    int d = threadIdx.x;
    float ah = 0.f, ac = 0.f;
    for (int k = 0; k < E; ++k) {
        float m = mf[k];
        ah += m * W_hid[(size_t)k * D + d];
        ac += m * W_cell[(size_t)k * D + d];
    }
    h[b * D + d] = ah + b_hid[d];
    c[b * D + d] = ac + b_cell[d];
}

// ---------------- fe = feat[order] @ Wf + bf  (M=12544,N=256,K=2048) ----------------
__global__ __launch_bounds__(256) void fe_gemm(const float* __restrict__ feat,
                                               const int* __restrict__ order,
                                               const float* __restrict__ Wf,
                                               const float* __restrict__ bf,
                                               float* __restrict__ fe) {
    __shared__ float As[16][68];
    __shared__ float Bs[16][64];
    __shared__ int srcRow[64];
    int rowBlock = blockIdx.x;   // 0..195
    int colBlock = blockIdx.y;   // 0..3
    int tid = threadIdx.x;
    if (tid < 64) {
        int gr = rowBlock * 64 + tid;
        int b = gr / P, p = gr % P;
        srcRow[tid] = order[b] * P + p;
    }
    __syncthreads();
    int tx = tid & 15, ty = tid >> 4;
    float acc[4][4] = {};
    for (int k0 = 0; k0 < E; k0 += 16) {
        #pragma unroll
        for (int i = tid; i < 64 * 16; i += 256) {
            int r = i >> 4, kk = i & 15;
            As[kk][r] = feat[(size_t)srcRow[r] * E + k0 + kk];
        }
        #pragma unroll
        for (int i = tid; i < 16 * 64; i += 256) {
            int kk = i >> 6, n = i & 63;
            Bs[kk][n] = Wf[(size_t)(k0 + kk) * H_ + colBlock * 64 + n];
        }
        __syncthreads();
        #pragma unroll
        for (int kk = 0; kk < 16; ++kk) {
            float4 av = *(const float4*)&As[kk][ty * 4];
            float4 bv = *(const float4*)&Bs[kk][tx * 4];
            acc[0][0] += av.x * bv.x; acc[0][1] += av.x * bv.y; acc[0][2] += av.x * bv.z; acc[0][3] += av.x * bv.w;
            acc[1][0] += av.y * bv.x; acc[1][1] += av.y * bv.y; acc[1][2] += av.y * bv.z; acc[1][3] += av.y * bv.w;
            acc[2][0] += av.z * bv.x; acc[2][1] += av.z * bv.y; acc[2][2] += av.z * bv.z; acc[2][3] += av.z * bv.w;
            acc[3][0] += av.w * bv.x; acc[3][1] += av.w * bv.y; acc[3][2] += av.w * bv.z; acc[3][3] += av.w * bv.w;
        }
        __syncthreads();
    }
    #pragma unroll
    for (int a = 0; a < 4; ++a) {
        int gr = rowBlock * 64 + ty * 4 + a;
        #pragma unroll
        for (int bb = 0; bb < 4; ++bb) {
            int col = colBlock * 64 + tx * 4 + bb;
            fe[(size_t)gr * H_ + col] = acc[a][bb] + bf[col];
        }
    }
}

// ---------------- attention: he, e, softmax, write w ----------------
__global__ __launch_bounds__(256) void attn_kernel(const int* __restrict__ target,
                                                   const float* __restrict__ Wh,
                                                   const float* __restrict__ bh,
                                                   const float* __restrict__ We,
                                                   const float* __restrict__ be,
                                                   const float* __restrict__ fe,
                                                   const float* __restrict__ h,
                                                   float* __restrict__ wbuf,
                                                   float* __restrict__ out2,
                                                   int t) {
    __shared__ float hs[D];
    __shared__ float hes[D];
    __shared__ float es[P];
    __shared__ float red[4];
    int b = blockIdx.x;
    int tid = threadIdx.x;
    hs[tid] = h[b * D + tid];
    __syncthreads();
    float acc = 0.f;
    for (int k = 0; k < D; ++k) acc += hs[k] * Wh[(size_t)k * H_ + tid];
    hes[tid] = acc + bh[tid];
    __syncthreads();
    int wave = tid >> 6, lane = tid & 63;
    for (int p = wave; p < P; p += 4) {
        const float* fp = fe + ((size_t)b * P + p) * H_;
        float s = 0.f;
        #pragma unroll
        for (int j = 0; j < 4; ++j) {
            int d = lane + j * 64;
            float v = fp[d] + hes[d];
            v = v > 0.f ? v : 0.f;
            s += v * We[d];
        }
        #pragma unroll
        for (int off = 32; off > 0; off >>= 1) s += __shfl_down(s, off);
        if (lane == 0) es[p] = s + be[0];
    }
    __syncthreads();
    // softmax over P
    float mx = -1e30f;
    for (int p = tid; p < P; p += 256) mx = fmaxf(mx, es[p]);
    #pragma unroll
    for (int off = 32; off > 0; off >>= 1) mx = fmaxf(mx, __shfl_down(mx, off));
    if (lane == 0) red[wave] = mx;
    __syncthreads();
    mx = fmaxf(fmaxf(red[0], red[1]), fmaxf(red[2], red[3]));
    __syncthreads();
    float sum = 0.f;
    for (int p = tid; p < P; p += 256) {
        float ex = expf(es[p] - mx);
        es[p] = ex;
        sum += ex;
    }
    #pragma unroll
    for (int off = 32; off > 0; off >>= 1) sum += __shfl_down(sum, off);
    if (lane == 0) red[wave] = sum;
    __syncthreads();
    sum = red[0] + red[1] + red[2] + red[3];
    float inv = 1.0f / sum;
    float m = (target[b] > t) ? 1.0f : 0.0f;
    for (int p = tid; p < P; p += 256) {
        float wv = es[p] * inv;
        wbuf[b * P + p] = wv;
        out2[((size_t)b * T + t) * P + p] = wv * m;
    }
}

// ---------------- ctx = (w*feat).sum(p) * sigmoid(h@W_gate+b_gate) ----------------
__global__ __launch_bounds__(256) void ctx_kernel(const float* __restrict__ feat,
                                                  const int* __restrict__ order,
                                                  const float* __restrict__ wbuf,
                                                  const float* __restrict__ W_gate,
                                                  const float* __restrict__ b_gate,
                                                  const float* __restrict__ h,
                                                  float* __restrict__ gctx) {
    __shared__ float ws_[P];
    __shared__ float hs[D];
    int b = blockIdx.x;
    int j = blockIdx.y;
    int tid = threadIdx.x;
    if (tid < P) ws_[tid] = wbuf[b * P + tid];
    hs[tid] = h[b * D + tid];
    __syncthreads();
    int e = j * 256 + tid;
    int src = order[b];
    const float* fp = feat + (size_t)src * P * E + e;
    float acc = 0.f;
    #pragma unroll 4
    for (int p = 0; p < P; ++p) acc += ws_[p] * fp[(size_t)p * E];
    float g = 0.f;
    for (int k = 0; k < D; ++k) g += hs[k] * W_gate[(size_t)k * E + e];
    g += b_gate[e];
    float sg = 1.0f / (1.0f + expf(-g));
    gctx[b * E + e] = sg * acc;
}

// ---------------- g-partials: [emb|ctx|h] @ [W_ih;W_hh], K split 4-way ----------------
__global__ __launch_bounds__(256) void lstm_gemm(const float* __restrict__ emb,
                                                 const int* __restrict__ cap_tok,
                                                 const int* __restrict__ order,
                                                 const float* __restrict__ gctx,
                                                 const float* __restrict__ h,
                                                 const float* __restrict__ W_ih,
                                                 const float* __restrict__ W_hh,
                                                 float* __restrict__ gpart,
                                                 int t) {
    __shared__ float As[16][68];
    __shared__ float Bs[16][64];
    __shared__ int toks[B];
    int cb = blockIdx.x;   // 0..15 col tile
    int ky = blockIdx.y;   // 0..3 K split
    int tid = threadIdx.x;
    if (tid < B) toks[tid] = cap_tok[order[tid] * L + t];
    __syncthreads();
    int tx = tid & 15, ty = tid >> 4;
    float acc[4][4] = {};
    int k0base = ky * 640;
    for (int k0 = k0base; k0 < k0base + 640; k0 += 16) {
        #pragma unroll
        for (int i = tid; i < 64 * 16; i += 256) {
            int r = i >> 4, kk = i & 15;
            int k = k0 + kk;
            float v;
            if (k < EM)            v = emb[(size_t)toks[r] * EM + k];
            else if (k < EM + E)   v = gctx[r * E + (k - EM)];
            else                   v = h[r * D + (k - EM - E)];
            As[kk][r] = v;
        }
        #pragma unroll
        for (int i = tid; i < 16 * 64; i += 256) {
            int kk = i >> 6, n = i & 63;
            int k = k0 + kk;
            float w = (k < EM + E) ? W_ih[(size_t)k * 1024 + cb * 64 + n]
                                   : W_hh[(size_t)(k - EM - E) * 1024 + cb * 64 + n];
            Bs[kk][n] = w;
        }
        __syncthreads();
        #pragma unroll
        for (int kk = 0; kk < 16; ++kk) {
            float4 av = *(const float4*)&As[kk][ty * 4];
            float4 bv = *(const float4*)&Bs[kk][tx * 4];
            acc[0][0] += av.x * bv.x; acc[0][1] += av.x * bv.y; acc[0][2] += av.x * bv.z; acc[0][3] += av.x * bv.w;
            acc[1][0] += av.y * bv.x; acc[1][1] += av.y * bv.y; acc[1][2] += av.y * bv.z; acc[1][3] += av.y * bv.w;
            acc[2][0] += av.z * bv.x; acc[2][1] += av.z * bv.y; acc[2][2] += av.z * bv.z; acc[2][3] += av.z * bv.w;
            acc[3][0] += av.w * bv.x; acc[3][1] += av.w * bv.y; acc[3][2] += av.w * bv.z; acc[3][3] += av.w * bv.w;
        }
        __syncthreads();
    }
    #pragma unroll
    for (int a = 0; a < 4; ++a) {
        int bidx = ty * 4 + a;
        #pragma unroll
        for (int bb = 0; bb < 4; ++bb) {
            int col = cb * 64 + tx * 4 + bb;
            gpart[((size_t)ky * B + bidx) * 1024 + col] = acc[a][bb];
        }
    }
}

// ---------------- LSTM pointwise: gates -> c_new, h_new; masked state update ----------------
__global__ __launch_bounds__(256) void lstm_pw(const float* __restrict__ gpart,
                                               const float* __restrict__ b_ih,
                                               const float* __restrict__ b_hh,
                                               const int* __restrict__ target,
                                               float* __restrict__ h,
                                               float* __restrict__ c,
                                               float* __restrict__ hn,
                                               int t) {
    int b = blockIdx.x, d = threadIdx.x;
    float gi = b_ih[d] + b_hh[d];
    float gf = b_ih[D + d] + b_hh[D + d];
    float gg = b_ih[2 * D + d] + b_hh[2 * D + d];
    float go = b_ih[3 * D + d] + b_hh[3 * D + d];
    #pragma unroll
    for (int ky = 0; ky < 4; ++ky) {
        const float* gp = gpart + ((size_t)ky * B + b) * 1024;
        gi += gp[d];
        gf += gp[D + d];
        gg += gp[2 * D + d];
        go += gp[3 * D + d];
    }
    float c_old = c[b * D + d];
    float si = 1.f / (1.f + expf(-gi));
    float sf = 1.f / (1.f + expf(-gf));
    float so = 1.f / (1.f + expf(-go));
    float cn = sf * c_old + si * tanhf(gg);
    float hnv = so * tanhf(cn);
    hn[b * D + d] = hnv;
    if (target[b] > t) {
        h[b * D + d] = hnv;
        c[b * D + d] = cn;
    }
}

// ---------------- head: pred = hn @ W_head + b_head, write pred*m ----------------
__global__ __launch_bounds__(256) void head_kernel(const float* __restrict__ hn,
                                                   const float* __restrict__ W_head,
                                                   const float* __restrict__ b_head,
                                                   const int* __restrict__ target,
                                                   float* __restrict__ out1,
                                                   int t) {
    __shared__ float hs[16][D];
    int cb = blockIdx.x;   // 0..156
    int bb = blockIdx.y;   // 0..3  (16 batch rows each)
    int tid = threadIdx.x;
    for (int i = tid; i < 16 * D; i += 256) {
        int r = i >> 8, k = i & 255;
        hs[r][k] = hn[(bb * 16 + r) * D + k];
    }
    __syncthreads();
    int col = cb * 64 + (tid & 63);
    int bloc = (tid >> 6) * 4;
    if (col < V) {
        float acc[4] = {0.f, 0.f, 0.f, 0.f};
        for (int k = 0; k < D; k += 4) {
            float w0 = W_head[(size_t)(k + 0) * V + col];
            float w1 = W_head[(size_t)(k + 1) * V + col];
            float w2 = W_head[(size_t)(k + 2) * V + col];
            float w3 = W_head[(size_t)(k + 3) * V + col];
            #pragma unroll
            for (int r = 0; r < 4; ++r) {
                float4 hv = *(const float4*)&hs[bloc + r][k];
                acc[r] += hv.x * w0 + hv.y * w1 + hv.z * w2 + hv.w * w3;
            }
        }
        float bh_ = b_head[col];
        #pragma unroll
        for (int r = 0; r < 4; ++r) {
            int brow = bb * 16 + bloc + r;
            float m = (target[brow] > t) ? 1.f : 0.f;
            out1[((size_t)brow * T + t) * V + col] = (acc[r] + bh_) * m;
        }
    }
}

extern "C" void kernel_launch(void* const* d_in, const int* in_sizes, int n_in,
                              void* d_out, int out_size, void* d_ws, size_t ws_size,
                              hipStream_t stream) {
    const float* feat   = (const float*)d_in[0];
    const int*   tok    = (const int*)d_in[1];
    const int*   clen   = (const int*)d_in[2];
    const float* Wf     = (const float*)d_in[3];
    const float* bf     = (const float*)d_in[4];
    const float* Wh     = (const float*)d_in[5];
    const float* bh     = (const float*)d_in[6];
    const float* We     = (const float*)d_in[7];
    const float* be     = (const float*)d_in[8];
    const float* emb    = (const float*)d_in[9];
    const float* W_ih   = (const float*)d_in[10];
    const float* b_ih   = (const float*)d_in[11];
    const float* W_hh   = (const float*)d_in[12];
    const float* b_hh   = (const float*)d_in[13];
    const float* W_hid  = (const float*)d_in[14];
    const float* b_hid  = (const float*)d_in[15];
    const float* W_cell = (const float*)d_in[16];
    const float* b_cell = (const float*)d_in[17];
    const float* W_gate = (const float*)d_in[18];
    const float* b_gate = (const float*)d_in[19];
    const float* W_head = (const float*)d_in[20];
    const float* b_head = (const float*)d_in[21];

    float* out1 = (float*)d_out;
    float* out2 = out1 + (size_t)B * T * V;

    char* wp = (char*)d_ws;
    int* order  = (int*)wp;            wp += 64 * sizeof(int);
    int* targetp = (int*)wp;           wp += 64 * sizeof(int);
    float* mean_feat = (float*)wp;     wp += (size_t)B * E * sizeof(float);
    float* fe   = (float*)wp;          wp += (size_t)B * P * H_ * sizeof(float);
    float* hbuf = (float*)wp;          wp += (size_t)B * D * sizeof(float);
    float* cbuf = (float*)wp;          wp += (size_t)B * D * sizeof(float);
    float* hnbuf = (float*)wp;         wp += (size_t)B * D * sizeof(float);
    float* wbuf = (float*)wp;          wp += (size_t)B * P * sizeof(float);
    float* gctx = (float*)wp;          wp += (size_t)B * E * sizeof(float);
    float* gpart = (float*)wp;         wp += (size_t)4 * B * 1024 * sizeof(float);

    sort_kernel<<<1, 64, 0, stream>>>(clen, order, targetp);
    mean_kernel<<<dim3(B, E / 256), 256, 0, stream>>>(feat, order, mean_feat);
    h0c0_kernel<<<B, 256, 0, stream>>>(mean_feat, W_hid, b_hid, W_cell, b_cell, hbuf, cbuf);
    fe_gemm<<<dim3(P, H_ / 64), 256, 0, stream>>>(feat, order, Wf, bf, fe);

    for (int t = 0; t < T; ++t) {
        attn_kernel<<<B, 256, 0, stream>>>(targetp, Wh, bh, We, be, fe, hbuf, wbuf, out2, t);
        ctx_kernel<<<dim3(B, E / 256), 256, 0, stream>>>(feat, order, wbuf, W_gate, b_gate, hbuf, gctx);
        lstm_gemm<<<dim3(16, 4), 256, 0, stream>>>(emb, tok, order, gctx, hbuf, W_ih, W_hh, gpart, t);
        lstm_pw<<<B, 256, 0, stream>>>(gpart, b_ih, b_hh, targetp, hbuf, cbuf, hnbuf, t);
        head_kernel<<<dim3((V + 63) / 64, 4), 256, 0, stream>>>(hnbuf, W_head, b_head, targetp, out1, t);
    }
}

// Round 2
// 4817.418 us; speedup vs baseline: 1.4511x; 1.4511x over previous
//
#include <hip/hip_runtime.h>
#include <math.h>

#define B 64
#define P 196
#define E 2048
#define D 256
#define H_ 256
#define EM 256
#define V 10000
#define L 32
#define T 31
#define KX 2560   // EM + E + D

// ---------------- sort: stable argsort descending by length ----------------
__global__ __launch_bounds__(64) void sort_kernel(const int* __restrict__ clen,
                                                  int* __restrict__ order,
                                                  int* __restrict__ target) {
    __shared__ int len_s[B];
    int i = threadIdx.x;
    len_s[i] = clen[i];
    __syncthreads();
    int li = len_s[i];
    int rank = 0;
    for (int j = 0; j < B; ++j) {
        int lj = len_s[j];
        if (lj > li || (lj == li && j < i)) rank++;
    }
    order[rank] = i;
    target[rank] = li - 1;
}

// ---------------- mean_feat[b][e] = mean_p feat[src][p][e] ----------------
__global__ __launch_bounds__(256) void mean_kernel(const float* __restrict__ feat,
                                                   const int* __restrict__ order,
                                                   float* __restrict__ mean_feat) {
    int b = blockIdx.x;
    int e = blockIdx.y * 256 + threadIdx.x;
    int src = order[b];
    const float* fp = feat + (size_t)src * P * E + e;
    float acc = 0.f;
    #pragma unroll 4
    for (int p = 0; p < P; ++p) acc += fp[(size_t)p * E];
    mean_feat[b * E + e] = acc * (1.0f / (float)P);
}

// ---------------- h0/c0 + xbuf init (emb_0, h0 slices) ----------------
__global__ __launch_bounds__(256) void h0c0_kernel(const float* __restrict__ mean_feat,
                                                   const float* __restrict__ W_hid,
                                                   const float* __restrict__ b_hid,
                                                   const float* __restrict__ W_cell,
                                                   const float* __restrict__ b_cell,
                                                   const float* __restrict__ emb,
                                                   const int* __restrict__ cap_tok,
                                                   const int* __restrict__ order,
                                                   float* __restrict__ h,
                                                   float* __restrict__ c,
                                                   float* __restrict__ xbuf) {
    __shared__ float mf[E];
    int b = blockIdx.x;
    for (int i = threadIdx.x; i < E; i += 256) mf[i] = mean_feat[b * E + i];
    __syncthreads();
    int d = threadIdx.x;
    float ah = 0.f, ac = 0.f;
    #pragma unroll 4
    for (int k = 0; k < E; ++k) {
        float m = mf[k];
        ah += m * W_hid[(size_t)k * D + d];
        ac += m * W_cell[(size_t)k * D + d];
    }
    float h0 = ah + b_hid[d];
    h[b * D + d] = h0;
    c[b * D + d] = ac + b_cell[d];
    // xbuf: [0:256)=emb_t, [2304:2560)=h
    int tok0 = cap_tok[order[b] * L + 0];
    xbuf[b * KX + d] = emb[(size_t)tok0 * EM + d];
    xbuf[b * KX + 2304 + d] = h0;
}

// ---------------- fe = feat[order] @ Wf + bf  (M=12544,N=256,K=2048) ----------------
// 128x64 tile, BK=32, float4 loads.
__global__ __launch_bounds__(256) void fe_gemm(const float* __restrict__ feat,
                                               const int* __restrict__ order,
                                               const float* __restrict__ Wf,
                                               const float* __restrict__ bf,
                                               float* __restrict__ fe) {
    __shared__ float As[32][132];  // [k][m]
    __shared__ float Bs[32][64];   // [k][n]
    __shared__ int srcRow[128];
    int rowBlock = blockIdx.x;   // 0..97
    int colBlock = blockIdx.y;   // 0..3
    int tid = threadIdx.x;
    if (tid < 128) {
        int gr = rowBlock * 128 + tid;
        int b = gr / P, p = gr % P;
        srcRow[tid] = order[b] * P + p;
    }
    __syncthreads();
    int tx = tid & 15, ty = tid >> 4;   // 16x16 threads, each 8 rows x 4 cols
    float acc[8][4] = {};
    for (int k0 = 0; k0 < E; k0 += 32) {
        // stage A: 128 rows x 32 k = 1024 float4 (kv fast for coalescing)
        #pragma unroll
        for (int q = 0; q < 4; ++q) {
            int idx = q * 256 + tid;
            int kv = idx & 7, m = idx >> 3;
            float4 v = *(const float4*)(feat + (size_t)srcRow[m] * E + k0 + kv * 4);
            As[kv * 4 + 0][m] = v.x;
            As[kv * 4 + 1][m] = v.y;
            As[kv * 4 + 2][m] = v.z;
            As[kv * 4 + 3][m] = v.w;
        }
        // stage B: 32 k x 64 n = 512 float4
        #pragma unroll
        for (int q = 0; q < 2; ++q) {
            int idx = q * 256 + tid;
            int n4 = idx & 15, kk = idx >> 4;
            float4 v = *(const float4*)(Wf + (size_t)(k0 + kk) * H_ + colBlock * 64 + n4 * 4);
            *(float4*)&Bs[kk][n4 * 4] = v;
        }
        __syncthreads();
        #pragma unroll
        for (int kk = 0; kk < 32; ++kk) {
            float4 a0 = *(const float4*)&As[kk][ty * 8];
            float4 a1 = *(const float4*)&As[kk][ty * 8 + 4];
            float4 bv = *(const float4*)&Bs[kk][tx * 4];
            float av[8] = {a0.x, a0.y, a0.z, a0.w, a1.x, a1.y, a1.z, a1.w};
            #pragma unroll
            for (int r = 0; r < 8; ++r) {
                acc[r][0] += av[r] * bv.x;
                acc[r][1] += av[r] * bv.y;
                acc[r][2] += av[r] * bv.z;
                acc[r][3] += av[r] * bv.w;
            }
        }
        __syncthreads();
    }
    float4 bias = *(const float4*)(bf + colBlock * 64 + tx * 4);
    #pragma unroll
    for (int r = 0; r < 8; ++r) {
        int gr = rowBlock * 128 + ty * 8 + r;
        float4 o;
        o.x = acc[r][0] + bias.x;
        o.y = acc[r][1] + bias.y;
        o.z = acc[r][2] + bias.z;
        o.w = acc[r][3] + bias.w;
        *(float4*)(fe + (size_t)gr * H_ + colBlock * 64 + tx * 4) = o;
    }
}

// ---------------- attention: he, e, softmax, write w ----------------
__global__ __launch_bounds__(256) void attn_kernel(const int* __restrict__ target,
                                                   const float* __restrict__ Wh,
                                                   const float* __restrict__ bh,
                                                   const float* __restrict__ We,
                                                   const float* __restrict__ be,
                                                   const float* __restrict__ fe,
                                                   const float* __restrict__ h,
                                                   float* __restrict__ wbuf,
                                                   float* __restrict__ out2,
                                                   int t) {
    __shared__ float hs[D];
    __shared__ float hes[D];
    __shared__ float es[P];
    __shared__ float red[4];
    int b = blockIdx.x;
    int tid = threadIdx.x;
    hs[tid] = h[b * D + tid];
    __syncthreads();
    float acc = 0.f;
    #pragma unroll 8
    for (int k = 0; k < D; ++k) acc += hs[k] * Wh[(size_t)k * H_ + tid];
    hes[tid] = acc + bh[tid];
    __syncthreads();
    int wave = tid >> 6, lane = tid & 63;
    // per-lane fragments (fixed 4 dims per lane)
    float4 he4 = *(const float4*)&hes[lane * 4];
    float4 we4 = *(const float4*)(We + lane * 4);
    for (int p = wave; p < P; p += 4) {
        float4 fv = *(const float4*)(fe + ((size_t)b * P + p) * H_ + lane * 4);
        float x0 = fv.x + he4.x; x0 = x0 > 0.f ? x0 : 0.f;
        float x1 = fv.y + he4.y; x1 = x1 > 0.f ? x1 : 0.f;
        float x2 = fv.z + he4.z; x2 = x2 > 0.f ? x2 : 0.f;
        float x3 = fv.w + he4.w; x3 = x3 > 0.f ? x3 : 0.f;
        float s = x0 * we4.x + x1 * we4.y + x2 * we4.z + x3 * we4.w;
        #pragma unroll
        for (int off = 32; off > 0; off >>= 1) s += __shfl_down(s, off);
        if (lane == 0) es[p] = s + be[0];
    }
    __syncthreads();
    // softmax over P
    float mx = -1e30f;
    for (int p = tid; p < P; p += 256) mx = fmaxf(mx, es[p]);
    #pragma unroll
    for (int off = 32; off > 0; off >>= 1) mx = fmaxf(mx, __shfl_down(mx, off));
    if (lane == 0) red[wave] = mx;
    __syncthreads();
    mx = fmaxf(fmaxf(red[0], red[1]), fmaxf(red[2], red[3]));
    __syncthreads();
    float sum = 0.f;
    for (int p = tid; p < P; p += 256) {
        float ex = expf(es[p] - mx);
        es[p] = ex;
        sum += ex;
    }
    #pragma unroll
    for (int off = 32; off > 0; off >>= 1) sum += __shfl_down(sum, off);
    if (lane == 0) red[wave] = sum;
    __syncthreads();
    sum = red[0] + red[1] + red[2] + red[3];
    float inv = 1.0f / sum;
    float m = (target[b] > t) ? 1.0f : 0.0f;
    for (int p = tid; p < P; p += 256) {
        float wv = es[p] * inv;
        wbuf[b * P + p] = wv;
        out2[((size_t)b * T + t) * P + p] = wv * m;
    }
}

// ---------------- ctx+gate: xbuf[b][256+e] = sigmoid(h@W_gate+b)[e] * (w*feat)[e] ----------------
__global__ __launch_bounds__(256) void ctx_kernel(const float* __restrict__ feat,
                                                  const int* __restrict__ order,
                                                  const float* __restrict__ wbuf,
                                                  const float* __restrict__ W_gate,
                                                  const float* __restrict__ b_gate,
                                                  const float* __restrict__ h,
                                                  float* __restrict__ xbuf) {
    __shared__ float ws_[P];
    __shared__ float hs[D];
    int b = blockIdx.x;
    int y = blockIdx.y;      // 0..1 (each block: 1024 cols)
    int tid = threadIdx.x;
    if (tid < P) ws_[tid] = wbuf[b * P + tid];
    hs[tid] = h[b * D + tid];
    __syncthreads();
    int src = order[b];
    const float4* f4 = (const float4*)(feat + (size_t)src * P * E);
    int c4 = y * 256 + tid;  // float4 column index in [0,512)
    float4 acc = {0.f, 0.f, 0.f, 0.f};
    #pragma unroll 4
    for (int p = 0; p < P; ++p) {
        float w = ws_[p];
        float4 fv = f4[(size_t)p * 512 + c4];
        acc.x += w * fv.x; acc.y += w * fv.y; acc.z += w * fv.z; acc.w += w * fv.w;
    }
    const float4* g4p = (const float4*)W_gate;
    float4 g = *(const float4*)(b_gate + c4 * 4);
    #pragma unroll 4
    for (int k = 0; k < D; ++k) {
        float hv = hs[k];
        float4 wv = g4p[(size_t)k * 512 + c4];
        g.x += hv * wv.x; g.y += hv * wv.y; g.z += hv * wv.z; g.w += hv * wv.w;
    }
    float4 o;
    o.x = acc.x / (1.f + expf(-g.x));
    o.y = acc.y / (1.f + expf(-g.y));
    o.z = acc.z / (1.f + expf(-g.z));
    o.w = acc.w / (1.f + expf(-g.w));
    *(float4*)(xbuf + (size_t)b * KX + EM + c4 * 4) = o;
}

// ---------------- gate GEMM: gpart[ky][b][1024] = xbuf[:, ky*640:(ky+1)*640] @ W[ky slice] ----------------
__global__ __launch_bounds__(256) void lstm_gemm(const float* __restrict__ xbuf,
                                                 const float* __restrict__ W_ih,
                                                 const float* __restrict__ W_hh,
                                                 float* __restrict__ gpart) {
    __shared__ float As[32][68];   // [k][m], m=64
    __shared__ float Bs[32][64];
    int cb = blockIdx.x;   // 0..15 col tile
    int ky = blockIdx.y;   // 0..3 K split
    int tid = threadIdx.x;
    int tx = tid & 15, ty = tid >> 4;
    float acc[4][4] = {};
    int k0base = ky * 640;
    for (int k0 = k0base; k0 < k0base + 640; k0 += 32) {
        // stage A: 64 rows x 32 k = 512 float4
        #pragma unroll
        for (int q = 0; q < 2; ++q) {
            int idx = q * 256 + tid;
            int kv = idx & 7, m = idx >> 3;
            float4 v = *(const float4*)(xbuf + (size_t)m * KX + k0 + kv * 4);
            As[kv * 4 + 0][m] = v.x;
            As[kv * 4 + 1][m] = v.y;
            As[kv * 4 + 2][m] = v.z;
            As[kv * 4 + 3][m] = v.w;
        }
        // stage B: 32 k x 64 n = 512 float4
        #pragma unroll
        for (int q = 0; q < 2; ++q) {
            int idx = q * 256 + tid;
            int n4 = idx & 15, kk = idx >> 4;
            int k = k0 + kk;
            const float* src = (k < EM + E) ? (W_ih + (size_t)k * 1024)
                                            : (W_hh + (size_t)(k - EM - E) * 1024);
            float4 v = *(const float4*)(src + cb * 64 + n4 * 4);
            *(float4*)&Bs[kk][n4 * 4] = v;
        }
        __syncthreads();
        #pragma unroll
        for (int kk = 0; kk < 32; ++kk) {
            float4 av = *(const float4*)&As[kk][ty * 4];
            float4 bv = *(const float4*)&Bs[kk][tx * 4];
            acc[0][0] += av.x * bv.x; acc[0][1] += av.x * bv.y; acc[0][2] += av.x * bv.z; acc[0][3] += av.x * bv.w;
            acc[1][0] += av.y * bv.x; acc[1][1] += av.y * bv.y; acc[1][2] += av.y * bv.z; acc[1][3] += av.y * bv.w;
            acc[2][0] += av.z * bv.x; acc[2][1] += av.z * bv.y; acc[2][2] += av.z * bv.z; acc[2][3] += av.z * bv.w;
            acc[3][0] += av.w * bv.x; acc[3][1] += av.w * bv.y; acc[3][2] += av.w * bv.z; acc[3][3] += av.w * bv.w;
        }
        __syncthreads();
    }
    #pragma unroll
    for (int a = 0; a < 4; ++a) {
        int bidx = ty * 4 + a;
        float4 o = {acc[a][0], acc[a][1], acc[a][2], acc[a][3]};
        *(float4*)(gpart + ((size_t)ky * B + bidx) * 1024 + cb * 64 + tx * 4) = o;
    }
}

// ---------------- LSTM pointwise; also stages next-step xbuf (h, emb_{t+1}) ----------------
__global__ __launch_bounds__(256) void lstm_pw(const float* __restrict__ gpart,
                                               const float* __restrict__ b_ih,
                                               const float* __restrict__ b_hh,
                                               const int* __restrict__ target,
                                               const float* __restrict__ emb,
                                               const int* __restrict__ cap_tok,
                                               const int* __restrict__ order,
                                               float* __restrict__ h,
                                               float* __restrict__ c,
                                               float* __restrict__ hn,
                                               float* __restrict__ xbuf,
                                               int t) {
    int b = blockIdx.x, d = threadIdx.x;
    float gi = b_ih[d] + b_hh[d];
    float gf = b_ih[D + d] + b_hh[D + d];
    float gg = b_ih[2 * D + d] + b_hh[2 * D + d];
    float go = b_ih[3 * D + d] + b_hh[3 * D + d];
    #pragma unroll
    for (int ky = 0; ky < 4; ++ky) {
        const float* gp = gpart + ((size_t)ky * B + b) * 1024;
        gi += gp[d];
        gf += gp[D + d];
        gg += gp[2 * D + d];
        go += gp[3 * D + d];
    }
    float c_old = c[b * D + d];
    float si = 1.f / (1.f + expf(-gi));
    float sf = 1.f / (1.f + expf(-gf));
    float so = 1.f / (1.f + expf(-go));
    float cn = sf * c_old + si * tanhf(gg);
    float hnv = so * tanhf(cn);
    hn[b * D + d] = hnv;
    float hm, cm;
    if (target[b] > t) { hm = hnv; cm = cn; } else { hm = h[b * D + d]; cm = c_old; }
    h[b * D + d] = hm;
    c[b * D + d] = cm;
    xbuf[(size_t)b * KX + 2304 + d] = hm;
    int tn = (t + 1 < L) ? (t + 1) : (L - 1);
    int tokn = cap_tok[order[b] * L + tn];
    xbuf[(size_t)b * KX + d] = emb[(size_t)tokn * EM + d];
}

// ---------------- head: pred = hn @ W_head + b_head, masked write ----------------
// grid (157, 2): 64 cols x 32 rows per block; hs in LDS, broadcast reads.
__global__ __launch_bounds__(256) void head_kernel(const float* __restrict__ hn,
                                                   const float* __restrict__ W_head,
                                                   const float* __restrict__ b_head,
                                                   const int* __restrict__ target,
                                                   float* __restrict__ out1,
                                                   int t) {
    __shared__ float hs[32][260];
    int cb = blockIdx.x;   // 0..156
    int bb = blockIdx.y;   // 0..1 (32 batch rows each)
    int tid = threadIdx.x;
    // stage 32x256 hs as float4
    #pragma unroll
    for (int q = 0; q < 8; ++q) {
        int idx = q * 256 + tid;           // 0..2047 float4s
        int r = idx >> 6, kq = idx & 63;
        float4 v = *(const float4*)(hn + (size_t)(bb * 32 + r) * D + kq * 4);
        *(float4*)&hs[r][kq * 4] = v;
    }
    __syncthreads();
    int col = cb * 64 + (tid & 63);
    int rgrp = (tid >> 6) * 8;             // 8 rows per thread
    if (col < V) {
        float acc[8] = {};
        for (int kq = 0; kq < 64; ++kq) {
            float w0 = W_head[(size_t)(kq * 4 + 0) * V + col];
            float w1 = W_head[(size_t)(kq * 4 + 1) * V + col];
            float w2 = W_head[(size_t)(kq * 4 + 2) * V + col];
            float w3 = W_head[(size_t)(kq * 4 + 3) * V + col];
            #pragma unroll
            for (int r = 0; r < 8; ++r) {
                float4 hv = *(const float4*)&hs[rgrp + r][kq * 4];
                acc[r] += hv.x * w0 + hv.y * w1 + hv.z * w2 + hv.w * w3;
            }
        }
        float bh_ = b_head[col];
        #pragma unroll
        for (int r = 0; r < 8; ++r) {
            int brow = bb * 32 + rgrp + r;
            float m = (target[brow] > t) ? 1.f : 0.f;
            out1[((size_t)brow * T + t) * V + col] = (acc[r] + bh_) * m;
        }
    }
}

extern "C" void kernel_launch(void* const* d_in, const int* in_sizes, int n_in,
                              void* d_out, int out_size, void* d_ws, size_t ws_size,
                              hipStream_t stream) {
    const float* feat   = (const float*)d_in[0];
    const int*   tok    = (const int*)d_in[1];
    const int*   clen   = (const int*)d_in[2];
    const float* Wf     = (const float*)d_in[3];
    const float* bf     = (const float*)d_in[4];
    const float* Wh     = (const float*)d_in[5];
    const float* bh     = (const float*)d_in[6];
    const float* We     = (const float*)d_in[7];
    const float* be     = (const float*)d_in[8];
    const float* emb    = (const float*)d_in[9];
    const float* W_ih   = (const float*)d_in[10];
    const float* b_ih   = (const float*)d_in[11];
    const float* W_hh   = (const float*)d_in[12];
    const float* b_hh   = (const float*)d_in[13];
    const float* W_hid  = (const float*)d_in[14];
    const float* b_hid  = (const float*)d_in[15];
    const float* W_cell = (const float*)d_in[16];
    const float* b_cell = (const float*)d_in[17];
    const float* W_gate = (const float*)d_in[18];
    const float* b_gate = (const float*)d_in[19];
    const float* W_head = (const float*)d_in[20];
    const float* b_head = (const float*)d_in[21];

    float* out1 = (float*)d_out;
    float* out2 = out1 + (size_t)B * T * V;

    char* wp = (char*)d_ws;
    int* order   = (int*)wp;           wp += 256;
    int* targetp = (int*)wp;           wp += 256;
    float* fe    = (float*)wp;         wp += (size_t)B * P * H_ * sizeof(float);
    float* hbuf  = (float*)wp;         wp += (size_t)B * D * sizeof(float);
    float* cbuf  = (float*)wp;         wp += (size_t)B * D * sizeof(float);
    float* hnbuf = (float*)wp;         wp += (size_t)B * D * sizeof(float);
    float* wbuf  = (float*)wp;         wp += (size_t)B * P * sizeof(float);
    float* xbuf  = (float*)wp;         wp += (size_t)B * KX * sizeof(float);
    float* gpart = (float*)wp;         wp += (size_t)4 * B * 1024 * sizeof(float);
    float* mean_feat = gpart;          // aliased: mean used only before the loop

    sort_kernel<<<1, 64, 0, stream>>>(clen, order, targetp);
    mean_kernel<<<dim3(B, E / 256), 256, 0, stream>>>(feat, order, mean_feat);
    h0c0_kernel<<<B, 256, 0, stream>>>(mean_feat, W_hid, b_hid, W_cell, b_cell,
                                       emb, tok, order, hbuf, cbuf, xbuf);
    fe_gemm<<<dim3(98, 4), 256, 0, stream>>>(feat, order, Wf, bf, fe);

    for (int t = 0; t < T; ++t) {
        attn_kernel<<<B, 256, 0, stream>>>(targetp, Wh, bh, We, be, fe, hbuf, wbuf, out2, t);
        ctx_kernel<<<dim3(B, 2), 256, 0, stream>>>(feat, order, wbuf, W_gate, b_gate, hbuf, xbuf);
        lstm_gemm<<<dim3(16, 4), 256, 0, stream>>>(xbuf, W_ih, W_hh, gpart);
        lstm_pw<<<B, 256, 0, stream>>>(gpart, b_ih, b_hh, targetp, emb, tok, order,
                                       hbuf, cbuf, hnbuf, xbuf, t);
        head_kernel<<<dim3(157, 2), 256, 0, stream>>>(hnbuf, W_head, b_head, targetp, out1, t);
    }
}

// Round 3
// 3359.646 us; speedup vs baseline: 2.0807x; 1.4339x over previous
//
#include <hip/hip_runtime.h>
#include <math.h>

#define B 64
#define P 196
#define E 2048
#define D 256
#define H_ 256
#define EM 256
#define V 10000
#define L 32
#define T 31
#define KX 2560   // EM + E + D

// ---------------- sort: stable argsort descending by length ----------------
__global__ __launch_bounds__(64) void sort_kernel(const int* __restrict__ clen,
                                                  int* __restrict__ order,
                                                  int* __restrict__ target) {
    __shared__ int len_s[B];
    int i = threadIdx.x;
    len_s[i] = clen[i];
    __syncthreads();
    int li = len_s[i];
    int rank = 0;
    for (int j = 0; j < B; ++j) {
        int lj = len_s[j];
        if (lj > li || (lj == li && j < i)) rank++;
    }
    order[rank] = i;
    target[rank] = li - 1;
}

// ---------------- mean_feat[b][e] = mean_p feat[src][p][e] ----------------
__global__ __launch_bounds__(256) void mean_kernel(const float* __restrict__ feat,
                                                   const int* __restrict__ order,
                                                   float* __restrict__ mean_feat) {
    int b = blockIdx.x;
    int e = blockIdx.y * 256 + threadIdx.x;
    int src = order[b];
    const float* fp = feat + (size_t)src * P * E + e;
    float acc = 0.f;
    #pragma unroll 4
    for (int p = 0; p < P; ++p) acc += fp[(size_t)p * E];
    mean_feat[b * E + e] = acc * (1.0f / (float)P);
}

// ---------------- h0c0 as split-K GEMM: hpart[ky][64][512] ----------------
// A = mean_feat (64 x 2048), Bmat = [W_hid | W_cell] (2048 x 512)
__global__ __launch_bounds__(256) void h0c0_gemm(const float* __restrict__ mean_feat,
                                                 const float* __restrict__ W_hid,
                                                 const float* __restrict__ W_cell,
                                                 float* __restrict__ hpart) {
    __shared__ float As[32][68];   // [k][m]
    __shared__ float Bs[32][64];   // [k][n]
    int cb = blockIdx.x;   // 0..7 col tile of 64 (N=512)
    int ky = blockIdx.y;   // 0..7 K split of 256
    int tid = threadIdx.x;
    int tx = tid & 15, ty = tid >> 4;
    const float* Wsrc;
    int ncol0;
    if (cb < 4) { Wsrc = W_hid;  ncol0 = cb * 64; }
    else        { Wsrc = W_cell; ncol0 = (cb - 4) * 64; }
    float acc[4][4] = {};
    for (int k0 = ky * 256; k0 < ky * 256 + 256; k0 += 32) {
        #pragma unroll
        for (int q = 0; q < 2; ++q) {
            int idx = q * 256 + tid;
            int kv = idx & 7, m = idx >> 3;
            float4 v = *(const float4*)(mean_feat + (size_t)m * E + k0 + kv * 4);
            As[kv * 4 + 0][m] = v.x;
            As[kv * 4 + 1][m] = v.y;
            As[kv * 4 + 2][m] = v.z;
            As[kv * 4 + 3][m] = v.w;
        }
        #pragma unroll
        for (int q = 0; q < 2; ++q) {
            int idx = q * 256 + tid;
            int n4 = idx & 15, kk = idx >> 4;
            float4 v = *(const float4*)(Wsrc + (size_t)(k0 + kk) * 256 + ncol0 + n4 * 4);
            *(float4*)&Bs[kk][n4 * 4] = v;
        }
        __syncthreads();
        #pragma unroll
        for (int kk = 0; kk < 32; ++kk) {
            float4 av = *(const float4*)&As[kk][ty * 4];
            float4 bv = *(const float4*)&Bs[kk][tx * 4];
            acc[0][0] += av.x * bv.x; acc[0][1] += av.x * bv.y; acc[0][2] += av.x * bv.z; acc[0][3] += av.x * bv.w;
            acc[1][0] += av.y * bv.x; acc[1][1] += av.y * bv.y; acc[1][2] += av.y * bv.z; acc[1][3] += av.y * bv.w;
            acc[2][0] += av.z * bv.x; acc[2][1] += av.z * bv.y; acc[2][2] += av.z * bv.z; acc[2][3] += av.z * bv.w;
            acc[3][0] += av.w * bv.x; acc[3][1] += av.w * bv.y; acc[3][2] += av.w * bv.z; acc[3][3] += av.w * bv.w;
        }
        __syncthreads();
    }
    #pragma unroll
    for (int a = 0; a < 4; ++a) {
        int row = ty * 4 + a;
        float4 o = {acc[a][0], acc[a][1], acc[a][2], acc[a][3]};
        *(float4*)(hpart + ((size_t)ky * B + row) * 512 + cb * 64 + tx * 4) = o;
    }
}

// ---------------- h0c0 reduce: sum partials, add bias, init h/c/xbuf ----------------
__global__ __launch_bounds__(256) void h0c0_reduce(const float* __restrict__ hpart,
                                                   const float* __restrict__ b_hid,
                                                   const float* __restrict__ b_cell,
                                                   const float* __restrict__ emb,
                                                   const int* __restrict__ cap_tok,
                                                   const int* __restrict__ order,
                                                   float* __restrict__ h,
                                                   float* __restrict__ c,
                                                   float* __restrict__ xbuf) {
    int b = blockIdx.x, tid = threadIdx.x;
    float s0 = 0.f, s1 = 0.f;
    #pragma unroll
    for (int ky = 0; ky < 8; ++ky) {
        const float* hp = hpart + ((size_t)ky * B + b) * 512;
        s0 += hp[tid];
        s1 += hp[256 + tid];
    }
    float h0 = s0 + b_hid[tid];
    h[b * D + tid] = h0;
    c[b * D + tid] = s1 + b_cell[tid];
    xbuf[(size_t)b * KX + 2304 + tid] = h0;
    int tok0 = cap_tok[order[b] * L + 0];
    xbuf[(size_t)b * KX + tid] = emb[(size_t)tok0 * EM + tid];
}

// ---------------- fe = feat[order] @ Wf + bf  (M=12544,N=256,K=2048) ----------------
__global__ __launch_bounds__(256) void fe_gemm(const float* __restrict__ feat,
                                               const int* __restrict__ order,
                                               const float* __restrict__ Wf,
                                               const float* __restrict__ bf,
                                               float* __restrict__ fe) {
    __shared__ float As[32][132];  // [k][m]
    __shared__ float Bs[32][64];   // [k][n]
    __shared__ int srcRow[128];
    int rowBlock = blockIdx.x;   // 0..97
    int colBlock = blockIdx.y;   // 0..3
    int tid = threadIdx.x;
    if (tid < 128) {
        int gr = rowBlock * 128 + tid;
        int b = gr / P, p = gr % P;
        srcRow[tid] = order[b] * P + p;
    }
    __syncthreads();
    int tx = tid & 15, ty = tid >> 4;
    float acc[8][4] = {};
    for (int k0 = 0; k0 < E; k0 += 32) {
        #pragma unroll
        for (int q = 0; q < 4; ++q) {
            int idx = q * 256 + tid;
            int kv = idx & 7, m = idx >> 3;
            float4 v = *(const float4*)(feat + (size_t)srcRow[m] * E + k0 + kv * 4);
            As[kv * 4 + 0][m] = v.x;
            As[kv * 4 + 1][m] = v.y;
            As[kv * 4 + 2][m] = v.z;
            As[kv * 4 + 3][m] = v.w;
        }
        #pragma unroll
        for (int q = 0; q < 2; ++q) {
            int idx = q * 256 + tid;
            int n4 = idx & 15, kk = idx >> 4;
            float4 v = *(const float4*)(Wf + (size_t)(k0 + kk) * H_ + colBlock * 64 + n4 * 4);
            *(float4*)&Bs[kk][n4 * 4] = v;
        }
        __syncthreads();
        #pragma unroll
        for (int kk = 0; kk < 32; ++kk) {
            float4 a0 = *(const float4*)&As[kk][ty * 8];
            float4 a1 = *(const float4*)&As[kk][ty * 8 + 4];
            float4 bv = *(const float4*)&Bs[kk][tx * 4];
            float av[8] = {a0.x, a0.y, a0.z, a0.w, a1.x, a1.y, a1.z, a1.w};
            #pragma unroll
            for (int r = 0; r < 8; ++r) {
                acc[r][0] += av[r] * bv.x;
                acc[r][1] += av[r] * bv.y;
                acc[r][2] += av[r] * bv.z;
                acc[r][3] += av[r] * bv.w;
            }
        }
        __syncthreads();
    }
    float4 bias = *(const float4*)(bf + colBlock * 64 + tx * 4);
    #pragma unroll
    for (int r = 0; r < 8; ++r) {
        int gr = rowBlock * 128 + ty * 8 + r;
        float4 o;
        o.x = acc[r][0] + bias.x;
        o.y = acc[r][1] + bias.y;
        o.z = acc[r][2] + bias.z;
        o.w = acc[r][3] + bias.w;
        *(float4*)(fe + (size_t)gr * H_ + colBlock * 64 + tx * 4) = o;
    }
}

// ---------------- attention: he, e, softmax, write w (active rows only) ----------------
__global__ __launch_bounds__(256) void attn_kernel(const int* __restrict__ target,
                                                   const float* __restrict__ Wh,
                                                   const float* __restrict__ bh,
                                                   const float* __restrict__ We,
                                                   const float* __restrict__ be,
                                                   const float* __restrict__ fe,
                                                   const float* __restrict__ h,
                                                   float* __restrict__ wbuf,
                                                   float* __restrict__ out2,
                                                   int t) {
    int b = blockIdx.x;
    if (target[b] <= t) return;   // inactive: out2 pre-zeroed, state frozen
    __shared__ float hs[D];
    __shared__ float hes[D];
    __shared__ float es[P];
    __shared__ float red[4];
    int tid = threadIdx.x;
    hs[tid] = h[b * D + tid];
    __syncthreads();
    float acc = 0.f;
    #pragma unroll 8
    for (int k = 0; k < D; ++k) acc += hs[k] * Wh[(size_t)k * H_ + tid];
    hes[tid] = acc + bh[tid];
    __syncthreads();
    int wave = tid >> 6, lane = tid & 63;
    float4 he4 = *(const float4*)&hes[lane * 4];
    float4 we4 = *(const float4*)(We + lane * 4);
    for (int p = wave; p < P; p += 4) {
        float4 fv = *(const float4*)(fe + ((size_t)b * P + p) * H_ + lane * 4);
        float x0 = fv.x + he4.x; x0 = x0 > 0.f ? x0 : 0.f;
        float x1 = fv.y + he4.y; x1 = x1 > 0.f ? x1 : 0.f;
        float x2 = fv.z + he4.z; x2 = x2 > 0.f ? x2 : 0.f;
        float x3 = fv.w + he4.w; x3 = x3 > 0.f ? x3 : 0.f;
        float s = x0 * we4.x + x1 * we4.y + x2 * we4.z + x3 * we4.w;
        #pragma unroll
        for (int off = 32; off > 0; off >>= 1) s += __shfl_down(s, off);
        if (lane == 0) es[p] = s + be[0];
    }
    __syncthreads();
    float mx = -1e30f;
    for (int p = tid; p < P; p += 256) mx = fmaxf(mx, es[p]);
    #pragma unroll
    for (int off = 32; off > 0; off >>= 1) mx = fmaxf(mx, __shfl_down(mx, off));
    if (lane == 0) red[wave] = mx;
    __syncthreads();
    mx = fmaxf(fmaxf(red[0], red[1]), fmaxf(red[2], red[3]));
    __syncthreads();
    float sum = 0.f;
    for (int p = tid; p < P; p += 256) {
        float ex = expf(es[p] - mx);
        es[p] = ex;
        sum += ex;
    }
    #pragma unroll
    for (int off = 32; off > 0; off >>= 1) sum += __shfl_down(sum, off);
    if (lane == 0) red[wave] = sum;
    __syncthreads();
    sum = red[0] + red[1] + red[2] + red[3];
    float inv = 1.0f / sum;
    for (int p = tid; p < P; p += 256) {
        float wv = es[p] * inv;
        wbuf[b * P + p] = wv;
        out2[((size_t)b * T + t) * P + p] = wv;   // active => mask=1
    }
}

// ---------------- ctx+gate -> xbuf[b][256:2304]; grid (B,8), 4-way P split ----------------
__global__ __launch_bounds__(256) void ctx_kernel(const float* __restrict__ feat,
                                                  const int* __restrict__ order,
                                                  const float* __restrict__ wbuf,
                                                  const float* __restrict__ W_gate,
                                                  const float* __restrict__ b_gate,
                                                  const float* __restrict__ h,
                                                  const int* __restrict__ target,
                                                  float* __restrict__ xbuf,
                                                  int t) {
    int b = blockIdx.x;
    if (target[b] <= t) return;
    int y = blockIdx.y;              // 0..7: cols [y*256, y*256+256)
    __shared__ float ws_[P];
    __shared__ float hs[D];
    __shared__ float4 rc[3][64];
    __shared__ float4 rg[3][64];
    int tid = threadIdx.x;
    if (tid < P) ws_[tid] = wbuf[b * P + tid];
    hs[tid] = h[b * D + tid];
    __syncthreads();
    int c4 = tid & 63, q = tid >> 6;
    int src = order[b];
    const float4* f4 = (const float4*)(feat + (size_t)src * P * E) + y * 64 + c4;
    float4 acc = {0.f, 0.f, 0.f, 0.f};
    // P = 196 = 4 * 49
    for (int p = q * 49; p < q * 49 + 49; ++p) {
        float w = ws_[p];
        float4 fv = f4[(size_t)p * 512];
        acc.x += w * fv.x; acc.y += w * fv.y; acc.z += w * fv.z; acc.w += w * fv.w;
    }
    const float4* g4 = (const float4*)W_gate + y * 64 + c4;
    float4 gacc = {0.f, 0.f, 0.f, 0.f};
    for (int k = q * 64; k < q * 64 + 64; ++k) {
        float hv = hs[k];
        float4 wv = g4[(size_t)k * 512];
        gacc.x += hv * wv.x; gacc.y += hv * wv.y; gacc.z += hv * wv.z; gacc.w += hv * wv.w;
    }
    if (q) { rc[q - 1][c4] = acc; rg[q - 1][c4] = gacc; }
    __syncthreads();
    if (q == 0) {
        #pragma unroll
        for (int j = 0; j < 3; ++j) {
            float4 a = rc[j][c4], g = rg[j][c4];
            acc.x += a.x; acc.y += a.y; acc.z += a.z; acc.w += a.w;
            gacc.x += g.x; gacc.y += g.y; gacc.z += g.z; gacc.w += g.w;
        }
        float4 gb = *(const float4*)(b_gate + (y * 64 + c4) * 4);
        float4 o;
        o.x = acc.x / (1.f + expf(-(gacc.x + gb.x)));
        o.y = acc.y / (1.f + expf(-(gacc.y + gb.y)));
        o.z = acc.z / (1.f + expf(-(gacc.z + gb.z)));
        o.w = acc.w / (1.f + expf(-(gacc.w + gb.w)));
        *(float4*)(xbuf + (size_t)b * KX + EM + (y * 64 + c4) * 4) = o;
    }
}

// ---------------- gate GEMM: K split 8-way ----------------
__global__ __launch_bounds__(256) void lstm_gemm(const float* __restrict__ xbuf,
                                                 const float* __restrict__ W_ih,
                                                 const float* __restrict__ W_hh,
                                                 float* __restrict__ gpart) {
    __shared__ float As[32][68];
    __shared__ float Bs[32][64];
    int cb = blockIdx.x;   // 0..15 col tile
    int ky = blockIdx.y;   // 0..7 K split (320 each)
    int tid = threadIdx.x;
    int tx = tid & 15, ty = tid >> 4;
    float acc[4][4] = {};
    int k0base = ky * 320;
    for (int k0 = k0base; k0 < k0base + 320; k0 += 32) {
        #pragma unroll
        for (int q = 0; q < 2; ++q) {
            int idx = q * 256 + tid;
            int kv = idx & 7, m = idx >> 3;
            float4 v = *(const float4*)(xbuf + (size_t)m * KX + k0 + kv * 4);
            As[kv * 4 + 0][m] = v.x;
            As[kv * 4 + 1][m] = v.y;
            As[kv * 4 + 2][m] = v.z;
            As[kv * 4 + 3][m] = v.w;
        }
        #pragma unroll
        for (int q = 0; q < 2; ++q) {
            int idx = q * 256 + tid;
            int n4 = idx & 15, kk = idx >> 4;
            int k = k0 + kk;
            const float* src = (k < EM + E) ? (W_ih + (size_t)k * 1024)
                                            : (W_hh + (size_t)(k - EM - E) * 1024);
            float4 v = *(const float4*)(src + cb * 64 + n4 * 4);
            *(float4*)&Bs[kk][n4 * 4] = v;
        }
        __syncthreads();
        #pragma unroll
        for (int kk = 0; kk < 32; ++kk) {
            float4 av = *(const float4*)&As[kk][ty * 4];
            float4 bv = *(const float4*)&Bs[kk][tx * 4];
            acc[0][0] += av.x * bv.x; acc[0][1] += av.x * bv.y; acc[0][2] += av.x * bv.z; acc[0][3] += av.x * bv.w;
            acc[1][0] += av.y * bv.x; acc[1][1] += av.y * bv.y; acc[1][2] += av.y * bv.z; acc[1][3] += av.y * bv.w;
            acc[2][0] += av.z * bv.x; acc[2][1] += av.z * bv.y; acc[2][2] += av.z * bv.z; acc[2][3] += av.z * bv.w;
            acc[3][0] += av.w * bv.x; acc[3][1] += av.w * bv.y; acc[3][2] += av.w * bv.z; acc[3][3] += av.w * bv.w;
        }
        __syncthreads();
    }
    #pragma unroll
    for (int a = 0; a < 4; ++a) {
        int bidx = ty * 4 + a;
        float4 o = {acc[a][0], acc[a][1], acc[a][2], acc[a][3]};
        *(float4*)(gpart + ((size_t)ky * B + bidx) * 1024 + cb * 64 + tx * 4) = o;
    }
}

// ---------------- LSTM pointwise (active rows only); stages next-step xbuf ----------------
__global__ __launch_bounds__(256) void lstm_pw(const float* __restrict__ gpart,
                                               const float* __restrict__ b_ih,
                                               const float* __restrict__ b_hh,
                                               const int* __restrict__ target,
                                               const float* __restrict__ emb,
                                               const int* __restrict__ cap_tok,
                                               const int* __restrict__ order,
                                               float* __restrict__ h,
                                               float* __restrict__ c,
                                               float* __restrict__ hn,
                                               float* __restrict__ xbuf,
                                               int t) {
    int b = blockIdx.x;
    if (target[b] <= t) return;   // frozen row: h/c/xbuf stay, head skips
    int d = threadIdx.x;
    float gi = b_ih[d] + b_hh[d];
    float gf = b_ih[D + d] + b_hh[D + d];
    float gg = b_ih[2 * D + d] + b_hh[2 * D + d];
    float go = b_ih[3 * D + d] + b_hh[3 * D + d];
    #pragma unroll
    for (int ky = 0; ky < 8; ++ky) {
        const float* gp = gpart + ((size_t)ky * B + b) * 1024;
        gi += gp[d];
        gf += gp[D + d];
        gg += gp[2 * D + d];
        go += gp[3 * D + d];
    }
    float c_old = c[b * D + d];
    float si = 1.f / (1.f + expf(-gi));
    float sf = 1.f / (1.f + expf(-gf));
    float so = 1.f / (1.f + expf(-go));
    float cn = sf * c_old + si * tanhf(gg);
    float hnv = so * tanhf(cn);
    hn[b * D + d] = hnv;
    h[b * D + d] = hnv;
    c[b * D + d] = cn;
    xbuf[(size_t)b * KX + 2304 + d] = hnv;
    int tn = (t + 1 < L) ? (t + 1) : (L - 1);
    int tokn = cap_tok[order[b] * L + tn];
    xbuf[(size_t)b * KX + d] = emb[(size_t)tokn * EM + d];
}

// ---------------- head: pred = hn @ W_head + b_head (active rows only) ----------------
__global__ __launch_bounds__(256) void head_kernel(const float* __restrict__ hn,
                                                   const float* __restrict__ W_head,
                                                   const float* __restrict__ b_head,
                                                   const int* __restrict__ target,
                                                   float* __restrict__ out1,
                                                   int t) {
    int bb = blockIdx.y;   // 0..1 (32 batch rows each)
    if (target[bb * 32] <= t) return;   // sorted: whole tile inactive
    __shared__ float hs[32][260];
    int cb = blockIdx.x;   // 0..156
    int tid = threadIdx.x;
    #pragma unroll
    for (int q = 0; q < 8; ++q) {
        int idx = q * 256 + tid;
        int r = idx >> 6, kq = idx & 63;
        float4 v = *(const float4*)(hn + (size_t)(bb * 32 + r) * D + kq * 4);
        *(float4*)&hs[r][kq * 4] = v;
    }
    __syncthreads();
    int col = cb * 64 + (tid & 63);
    int rgrp = (tid >> 6) * 8;
    if (col < V) {
        float acc[8] = {};
        for (int kq = 0; kq < 64; ++kq) {
            float w0 = W_head[(size_t)(kq * 4 + 0) * V + col];
            float w1 = W_head[(size_t)(kq * 4 + 1) * V + col];
            float w2 = W_head[(size_t)(kq * 4 + 2) * V + col];
            float w3 = W_head[(size_t)(kq * 4 + 3) * V + col];
            #pragma unroll
            for (int r = 0; r < 8; ++r) {
                float4 hv = *(const float4*)&hs[rgrp + r][kq * 4];
                acc[r] += hv.x * w0 + hv.y * w1 + hv.z * w2 + hv.w * w3;
            }
        }
        float bh_ = b_head[col];
        #pragma unroll
        for (int r = 0; r < 8; ++r) {
            int brow = bb * 32 + rgrp + r;
            if (target[brow] > t)
                out1[((size_t)brow * T + t) * V + col] = acc[r] + bh_;
        }
    }
}

extern "C" void kernel_launch(void* const* d_in, const int* in_sizes, int n_in,
                              void* d_out, int out_size, void* d_ws, size_t ws_size,
                              hipStream_t stream) {
    const float* feat   = (const float*)d_in[0];
    const int*   tok    = (const int*)d_in[1];
    const int*   clen   = (const int*)d_in[2];
    const float* Wf     = (const float*)d_in[3];
    const float* bf     = (const float*)d_in[4];
    const float* Wh     = (const float*)d_in[5];
    const float* bh     = (const float*)d_in[6];
    const float* We     = (const float*)d_in[7];
    const float* be     = (const float*)d_in[8];
    const float* emb    = (const float*)d_in[9];
    const float* W_ih   = (const float*)d_in[10];
    const float* b_ih   = (const float*)d_in[11];
    const float* W_hh   = (const float*)d_in[12];
    const float* b_hh   = (const float*)d_in[13];
    const float* W_hid  = (const float*)d_in[14];
    const float* b_hid  = (const float*)d_in[15];
    const float* W_cell = (const float*)d_in[16];
    const float* b_cell = (const float*)d_in[17];
    const float* W_gate = (const float*)d_in[18];
    const float* b_gate = (const float*)d_in[19];
    const float* W_head = (const float*)d_in[20];
    const float* b_head = (const float*)d_in[21];

    float* out1 = (float*)d_out;
    float* out2 = out1 + (size_t)B * T * V;

    char* wp = (char*)d_ws;
    int* order   = (int*)wp;           wp += 256;
    int* targetp = (int*)wp;           wp += 256;
    float* fe    = (float*)wp;         wp += (size_t)B * P * H_ * sizeof(float);
    float* hbuf  = (float*)wp;         wp += (size_t)B * D * sizeof(float);
    float* cbuf  = (float*)wp;         wp += (size_t)B * D * sizeof(float);
    float* hnbuf = (float*)wp;         wp += (size_t)B * D * sizeof(float);
    float* wbuf  = (float*)wp;         wp += (size_t)B * P * sizeof(float);
    float* xbuf  = (float*)wp;         wp += (size_t)B * KX * sizeof(float);
    float* gpart = (float*)wp;         wp += (size_t)8 * B * 1024 * sizeof(float);
    float* mean_feat = (float*)wp;     wp += (size_t)B * E * sizeof(float);
    float* hpart = (float*)wp;         wp += (size_t)8 * B * 512 * sizeof(float);

    // zero both outputs once; masked elements are never written afterwards
    hipMemsetAsync(d_out, 0, (size_t)out_size * sizeof(float), stream);

    sort_kernel<<<1, 64, 0, stream>>>(clen, order, targetp);
    mean_kernel<<<dim3(B, E / 256), 256, 0, stream>>>(feat, order, mean_feat);
    h0c0_gemm<<<dim3(8, 8), 256, 0, stream>>>(mean_feat, W_hid, W_cell, hpart);
    h0c0_reduce<<<B, 256, 0, stream>>>(hpart, b_hid, b_cell, emb, tok, order,
                                       hbuf, cbuf, xbuf);
    fe_gemm<<<dim3(98, 4), 256, 0, stream>>>(feat, order, Wf, bf, fe);

    for (int t = 0; t < T; ++t) {
        attn_kernel<<<B, 256, 0, stream>>>(targetp, Wh, bh, We, be, fe, hbuf, wbuf, out2, t);
        ctx_kernel<<<dim3(B, 8), 256, 0, stream>>>(feat, order, wbuf, W_gate, b_gate,
                                                   hbuf, targetp, xbuf, t);
        lstm_gemm<<<dim3(16, 8), 256, 0, stream>>>(xbuf, W_ih, W_hh, gpart);
        lstm_pw<<<B, 256, 0, stream>>>(gpart, b_ih, b_hh, targetp, emb, tok, order,
                                       hbuf, cbuf, hnbuf, xbuf, t);
        head_kernel<<<dim3(157, 2), 256, 0, stream>>>(hnbuf, W_head, b_head, targetp, out1, t);
    }
}

// Round 4
// 2872.707 us; speedup vs baseline: 2.4334x; 1.1695x over previous
//
#include <hip/hip_runtime.h>
#include <math.h>

#define B 64
#define P 196
#define E 2048
#define D 256
#define H_ 256
#define EM 256
#define V 10000
#define L 32
#define T 31
#define KX 2560   // EM + E + D

// ---------------- sort: stable argsort descending by length ----------------
__global__ __launch_bounds__(64) void sort_kernel(const int* __restrict__ clen,
                                                  int* __restrict__ order,
                                                  int* __restrict__ target) {
    __shared__ int len_s[B];
    int i = threadIdx.x;
    len_s[i] = clen[i];
    __syncthreads();
    int li = len_s[i];
    int rank = 0;
    for (int j = 0; j < B; ++j) {
        int lj = len_s[j];
        if (lj > li || (lj == li && j < i)) rank++;
    }
    order[rank] = i;
    target[rank] = li - 1;
}

// ---------------- mean_feat[b][e] = mean_p feat[src][p][e] ----------------
__global__ __launch_bounds__(256) void mean_kernel(const float* __restrict__ feat,
                                                   const int* __restrict__ order,
                                                   float* __restrict__ mean_feat) {
    int b = blockIdx.x;
    int e = blockIdx.y * 256 + threadIdx.x;
    int src = order[b];
    const float* fp = feat + (size_t)src * P * E + e;
    float acc = 0.f;
    #pragma unroll 4
    for (int p = 0; p < P; ++p) acc += fp[(size_t)p * E];
    mean_feat[b * E + e] = acc * (1.0f / (float)P);
}

// ---------------- h0c0 as split-K GEMM: hpart[ky][64][512] ----------------
__global__ __launch_bounds__(256) void h0c0_gemm(const float* __restrict__ mean_feat,
                                                 const float* __restrict__ W_hid,
                                                 const float* __restrict__ W_cell,
                                                 float* __restrict__ hpart) {
    __shared__ float As[32][68];
    __shared__ float Bs[32][64];
    int cb = blockIdx.x;   // 0..7
    int ky = blockIdx.y;   // 0..7
    int tid = threadIdx.x;
    int tx = tid & 15, ty = tid >> 4;
    const float* Wsrc;
    int ncol0;
    if (cb < 4) { Wsrc = W_hid;  ncol0 = cb * 64; }
    else        { Wsrc = W_cell; ncol0 = (cb - 4) * 64; }
    float acc[4][4] = {};
    for (int k0 = ky * 256; k0 < ky * 256 + 256; k0 += 32) {
        #pragma unroll
        for (int q = 0; q < 2; ++q) {
            int idx = q * 256 + tid;
            int kv = idx & 7, m = idx >> 3;
            float4 v = *(const float4*)(mean_feat + (size_t)m * E + k0 + kv * 4);
            As[kv * 4 + 0][m] = v.x;
            As[kv * 4 + 1][m] = v.y;
            As[kv * 4 + 2][m] = v.z;
            As[kv * 4 + 3][m] = v.w;
        }
        #pragma unroll
        for (int q = 0; q < 2; ++q) {
            int idx = q * 256 + tid;
            int n4 = idx & 15, kk = idx >> 4;
            float4 v = *(const float4*)(Wsrc + (size_t)(k0 + kk) * 256 + ncol0 + n4 * 4);
            *(float4*)&Bs[kk][n4 * 4] = v;
        }
        __syncthreads();
        #pragma unroll
        for (int kk = 0; kk < 32; ++kk) {
            float4 av = *(const float4*)&As[kk][ty * 4];
            float4 bv = *(const float4*)&Bs[kk][tx * 4];
            acc[0][0] += av.x * bv.x; acc[0][1] += av.x * bv.y; acc[0][2] += av.x * bv.z; acc[0][3] += av.x * bv.w;
            acc[1][0] += av.y * bv.x; acc[1][1] += av.y * bv.y; acc[1][2] += av.y * bv.z; acc[1][3] += av.y * bv.w;
            acc[2][0] += av.z * bv.x; acc[2][1] += av.z * bv.y; acc[2][2] += av.z * bv.z; acc[2][3] += av.z * bv.w;
            acc[3][0] += av.w * bv.x; acc[3][1] += av.w * bv.y; acc[3][2] += av.w * bv.z; acc[3][3] += av.w * bv.w;
        }
        __syncthreads();
    }
    #pragma unroll
    for (int a = 0; a < 4; ++a) {
        int row = ty * 4 + a;
        float4 o = {acc[a][0], acc[a][1], acc[a][2], acc[a][3]};
        *(float4*)(hpart + ((size_t)ky * B + row) * 512 + cb * 64 + tx * 4) = o;
    }
}

// ---------------- h0c0 reduce: sum partials, add bias, init h/c/xbuf ----------------
__global__ __launch_bounds__(256) void h0c0_reduce(const float* __restrict__ hpart,
                                                   const float* __restrict__ b_hid,
                                                   const float* __restrict__ b_cell,
                                                   const float* __restrict__ emb,
                                                   const int* __restrict__ cap_tok,
                                                   const int* __restrict__ order,
                                                   float* __restrict__ h,
                                                   float* __restrict__ c,
                                                   float* __restrict__ xbuf) {
    int b = blockIdx.x, tid = threadIdx.x;
    float s0 = 0.f, s1 = 0.f;
    #pragma unroll
    for (int ky = 0; ky < 8; ++ky) {
        const float* hp = hpart + ((size_t)ky * B + b) * 512;
        s0 += hp[tid];
        s1 += hp[256 + tid];
    }
    float h0 = s0 + b_hid[tid];
    h[b * D + tid] = h0;
    c[b * D + tid] = s1 + b_cell[tid];
    xbuf[(size_t)b * KX + 2304 + tid] = h0;
    int tok0 = cap_tok[order[b] * L + 0];
    xbuf[(size_t)b * KX + tid] = emb[(size_t)tok0 * EM + tid];
}

// ---------------- fe = feat[order] @ Wf + bf; 64x64 tiles, grid (196,4) ----------------
__global__ __launch_bounds__(256) void fe_gemm(const float* __restrict__ feat,
                                               const int* __restrict__ order,
                                               const float* __restrict__ Wf,
                                               const float* __restrict__ bf,
                                               float* __restrict__ fe) {
    __shared__ float As[32][68];
    __shared__ float Bs[32][64];
    __shared__ int srcRow[64];
    int rowBlock = blockIdx.x;   // 0..195
    int colBlock = blockIdx.y;   // 0..3
    int tid = threadIdx.x;
    if (tid < 64) {
        int gr = rowBlock * 64 + tid;
        int b = gr / P, p = gr % P;
        srcRow[tid] = order[b] * P + p;
    }
    __syncthreads();
    int tx = tid & 15, ty = tid >> 4;
    float acc[4][4] = {};
    for (int k0 = 0; k0 < E; k0 += 32) {
        #pragma unroll
        for (int q = 0; q < 2; ++q) {
            int idx = q * 256 + tid;
            int kv = idx & 7, m = idx >> 3;
            float4 v = *(const float4*)(feat + (size_t)srcRow[m] * E + k0 + kv * 4);
            As[kv * 4 + 0][m] = v.x;
            As[kv * 4 + 1][m] = v.y;
            As[kv * 4 + 2][m] = v.z;
            As[kv * 4 + 3][m] = v.w;
        }
        {
            int n4 = tid & 15, kk = tid >> 4;   // kk 0..15
            float4 v = *(const float4*)(Wf + (size_t)(k0 + kk) * H_ + colBlock * 64 + n4 * 4);
            *(float4*)&Bs[kk][n4 * 4] = v;
            int kk2 = kk + 16;
            float4 v2 = *(const float4*)(Wf + (size_t)(k0 + kk2) * H_ + colBlock * 64 + n4 * 4);
            *(float4*)&Bs[kk2][n4 * 4] = v2;
        }
        __syncthreads();
        #pragma unroll
        for (int kk = 0; kk < 32; ++kk) {
            float4 av = *(const float4*)&As[kk][ty * 4];
            float4 bv = *(const float4*)&Bs[kk][tx * 4];
            acc[0][0] += av.x * bv.x; acc[0][1] += av.x * bv.y; acc[0][2] += av.x * bv.z; acc[0][3] += av.x * bv.w;
            acc[1][0] += av.y * bv.x; acc[1][1] += av.y * bv.y; acc[1][2] += av.y * bv.z; acc[1][3] += av.y * bv.w;
            acc[2][0] += av.z * bv.x; acc[2][1] += av.z * bv.y; acc[2][2] += av.z * bv.z; acc[2][3] += av.z * bv.w;
            acc[3][0] += av.w * bv.x; acc[3][1] += av.w * bv.y; acc[3][2] += av.w * bv.z; acc[3][3] += av.w * bv.w;
        }
        __syncthreads();
    }
    float4 bias = *(const float4*)(bf + colBlock * 64 + tx * 4);
    #pragma unroll
    for (int a = 0; a < 4; ++a) {
        int gr = rowBlock * 64 + ty * 4 + a;
        float4 o;
        o.x = acc[a][0] + bias.x;
        o.y = acc[a][1] + bias.y;
        o.z = acc[a][2] + bias.z;
        o.w = acc[a][3] + bias.w;
        *(float4*)(fe + (size_t)gr * H_ + colBlock * 64 + tx * 4) = o;
    }
}

// ---------------- fused: LSTM pointwise (step t-1) + attention (step t) ----------------
__global__ __launch_bounds__(256) void attn_pw(const int* __restrict__ target,
                                               const float* __restrict__ gpart,
                                               const float* __restrict__ b_ih,
                                               const float* __restrict__ b_hh,
                                               const float* __restrict__ emb,
                                               const int* __restrict__ cap_tok,
                                               const int* __restrict__ order,
                                               const float* __restrict__ Wh,
                                               const float* __restrict__ bh,
                                               const float* __restrict__ We,
                                               const float* __restrict__ be,
                                               const float* __restrict__ fe,
                                               float* __restrict__ h,
                                               float* __restrict__ c,
                                               float* __restrict__ hn_all,
                                               float* __restrict__ xbuf,
                                               float* __restrict__ wbuf,
                                               float* __restrict__ out2,
                                               int t) {
    int b = blockIdx.x;
    int tgt = target[b];
    bool pw_active = (t > 0) && (tgt > t - 1);
    bool at_active = (tgt > t);
    if (!pw_active && !at_active) return;
    __shared__ float hs[D];
    __shared__ float hes[D];
    __shared__ float es[P];
    __shared__ float red[4];
    int tid = threadIdx.x;
    if (pw_active) {
        int d = tid;
        float gi = b_ih[d] + b_hh[d];
        float gf = b_ih[D + d] + b_hh[D + d];
        float gg = b_ih[2 * D + d] + b_hh[2 * D + d];
        float go = b_ih[3 * D + d] + b_hh[3 * D + d];
        #pragma unroll
        for (int ky = 0; ky < 8; ++ky) {
            const float* gp = gpart + ((size_t)ky * B + b) * 1024;
            gi += gp[d];
            gf += gp[D + d];
            gg += gp[2 * D + d];
            go += gp[3 * D + d];
        }
        float c_old = c[b * D + d];
        float si = 1.f / (1.f + expf(-gi));
        float sf = 1.f / (1.f + expf(-gf));
        float so = 1.f / (1.f + expf(-go));
        float cn = sf * c_old + si * tanhf(gg);
        float hnv = so * tanhf(cn);
        c[b * D + d] = cn;
        h[b * D + d] = hnv;
        hs[d] = hnv;
        hn_all[((size_t)(t - 1) * B + b) * D + d] = hnv;
        xbuf[(size_t)b * KX + 2304 + d] = hnv;
        int tokn = cap_tok[order[b] * L + t];
        xbuf[(size_t)b * KX + d] = emb[(size_t)tokn * EM + d];
    } else {
        hs[tid] = h[b * D + tid];
    }
    __syncthreads();
    if (!at_active) return;
    float acc = 0.f;
    #pragma unroll 8
    for (int k = 0; k < D; ++k) acc += hs[k] * Wh[(size_t)k * H_ + tid];
    hes[tid] = acc + bh[tid];
    __syncthreads();
    int wave = tid >> 6, lane = tid & 63;
    float4 he4 = *(const float4*)&hes[lane * 4];
    float4 we4 = *(const float4*)(We + lane * 4);
    for (int p = wave; p < P; p += 4) {
        float4 fv = *(const float4*)(fe + ((size_t)b * P + p) * H_ + lane * 4);
        float x0 = fv.x + he4.x; x0 = x0 > 0.f ? x0 : 0.f;
        float x1 = fv.y + he4.y; x1 = x1 > 0.f ? x1 : 0.f;
        float x2 = fv.z + he4.z; x2 = x2 > 0.f ? x2 : 0.f;
        float x3 = fv.w + he4.w; x3 = x3 > 0.f ? x3 : 0.f;
        float s = x0 * we4.x + x1 * we4.y + x2 * we4.z + x3 * we4.w;
        #pragma unroll
        for (int off = 32; off > 0; off >>= 1) s += __shfl_down(s, off);
        if (lane == 0) es[p] = s + be[0];
    }
    __syncthreads();
    float mx = -1e30f;
    for (int p = tid; p < P; p += 256) mx = fmaxf(mx, es[p]);
    #pragma unroll
    for (int off = 32; off > 0; off >>= 1) mx = fmaxf(mx, __shfl_down(mx, off));
    if (lane == 0) red[wave] = mx;
    __syncthreads();
    mx = fmaxf(fmaxf(red[0], red[1]), fmaxf(red[2], red[3]));
    __syncthreads();
    float sum = 0.f;
    for (int p = tid; p < P; p += 256) {
        float ex = expf(es[p] - mx);
        es[p] = ex;
        sum += ex;
    }
    #pragma unroll
    for (int off = 32; off > 0; off >>= 1) sum += __shfl_down(sum, off);
    if (lane == 0) red[wave] = sum;
    __syncthreads();
    sum = red[0] + red[1] + red[2] + red[3];
    float inv = 1.0f / sum;
    for (int p = tid; p < P; p += 256) {
        float wv = es[p] * inv;
        wbuf[b * P + p] = wv;
        out2[((size_t)b * T + t) * P + p] = wv;
    }
}

// ---------------- ctx+gate -> xbuf[b][256:2304]; grid (B,8) ----------------
__global__ __launch_bounds__(256) void ctx_kernel(const float* __restrict__ feat,
                                                  const int* __restrict__ order,
                                                  const float* __restrict__ wbuf,
                                                  const float* __restrict__ W_gate,
                                                  const float* __restrict__ b_gate,
                                                  const float* __restrict__ h,
                                                  const int* __restrict__ target,
                                                  float* __restrict__ xbuf,
                                                  int t) {
    int b = blockIdx.x;
    if (target[b] <= t) return;
    int y = blockIdx.y;
    __shared__ float ws_[P];
    __shared__ float hs[D];
    __shared__ float4 rc[3][64];
    __shared__ float4 rg[3][64];
    int tid = threadIdx.x;
    if (tid < P) ws_[tid] = wbuf[b * P + tid];
    hs[tid] = h[b * D + tid];
    __syncthreads();
    int c4 = tid & 63, q = tid >> 6;
    int src = order[b];
    const float4* f4 = (const float4*)(feat + (size_t)src * P * E) + y * 64 + c4;
    float4 acc = {0.f, 0.f, 0.f, 0.f};
    for (int p = q * 49; p < q * 49 + 49; ++p) {
        float w = ws_[p];
        float4 fv = f4[(size_t)p * 512];
        acc.x += w * fv.x; acc.y += w * fv.y; acc.z += w * fv.z; acc.w += w * fv.w;
    }
    const float4* g4 = (const float4*)W_gate + y * 64 + c4;
    float4 gacc = {0.f, 0.f, 0.f, 0.f};
    for (int k = q * 64; k < q * 64 + 64; ++k) {
        float hv = hs[k];
        float4 wv = g4[(size_t)k * 512];
        gacc.x += hv * wv.x; gacc.y += hv * wv.y; gacc.z += hv * wv.z; gacc.w += hv * wv.w;
    }
    if (q) { rc[q - 1][c4] = acc; rg[q - 1][c4] = gacc; }
    __syncthreads();
    if (q == 0) {
        #pragma unroll
        for (int j = 0; j < 3; ++j) {
            float4 a = rc[j][c4], g = rg[j][c4];
            acc.x += a.x; acc.y += a.y; acc.z += a.z; acc.w += a.w;
            gacc.x += g.x; gacc.y += g.y; gacc.z += g.z; gacc.w += g.w;
        }
        float4 gb = *(const float4*)(b_gate + (y * 64 + c4) * 4);
        float4 o;
        o.x = acc.x / (1.f + expf(-(gacc.x + gb.x)));
        o.y = acc.y / (1.f + expf(-(gacc.y + gb.y)));
        o.z = acc.z / (1.f + expf(-(gacc.z + gb.z)));
        o.w = acc.w / (1.f + expf(-(gacc.w + gb.w)));
        *(float4*)(xbuf + (size_t)b * KX + EM + (y * 64 + c4) * 4) = o;
    }
}

// ---------------- gate GEMM: K split 8-way ----------------
__global__ __launch_bounds__(256) void lstm_gemm(const float* __restrict__ xbuf,
                                                 const float* __restrict__ W_ih,
                                                 const float* __restrict__ W_hh,
                                                 float* __restrict__ gpart) {
    __shared__ float As[32][68];
    __shared__ float Bs[32][64];
    int cb = blockIdx.x;   // 0..15
    int ky = blockIdx.y;   // 0..7
    int tid = threadIdx.x;
    int tx = tid & 15, ty = tid >> 4;
    float acc[4][4] = {};
    int k0base = ky * 320;
    for (int k0 = k0base; k0 < k0base + 320; k0 += 32) {
        #pragma unroll
        for (int q = 0; q < 2; ++q) {
            int idx = q * 256 + tid;
            int kv = idx & 7, m = idx >> 3;
            float4 v = *(const float4*)(xbuf + (size_t)m * KX + k0 + kv * 4);
            As[kv * 4 + 0][m] = v.x;
            As[kv * 4 + 1][m] = v.y;
            As[kv * 4 + 2][m] = v.z;
            As[kv * 4 + 3][m] = v.w;
        }
        #pragma unroll
        for (int q = 0; q < 2; ++q) {
            int idx = q * 256 + tid;
            int n4 = idx & 15, kk = idx >> 4;
            int k = k0 + kk;
            const float* src = (k < EM + E) ? (W_ih + (size_t)k * 1024)
                                            : (W_hh + (size_t)(k - EM - E) * 1024);
            float4 v = *(const float4*)(src + cb * 64 + n4 * 4);
            *(float4*)&Bs[kk][n4 * 4] = v;
        }
        __syncthreads();
        #pragma unroll
        for (int kk = 0; kk < 32; ++kk) {
            float4 av = *(const float4*)&As[kk][ty * 4];
            float4 bv = *(const float4*)&Bs[kk][tx * 4];
            acc[0][0] += av.x * bv.x; acc[0][1] += av.x * bv.y; acc[0][2] += av.x * bv.z; acc[0][3] += av.x * bv.w;
            acc[1][0] += av.y * bv.x; acc[1][1] += av.y * bv.y; acc[1][2] += av.y * bv.z; acc[1][3] += av.y * bv.w;
            acc[2][0] += av.z * bv.x; acc[2][1] += av.z * bv.y; acc[2][2] += av.z * bv.z; acc[2][3] += av.z * bv.w;
            acc[3][0] += av.w * bv.x; acc[3][1] += av.w * bv.y; acc[3][2] += av.w * bv.z; acc[3][3] += av.w * bv.w;
        }
        __syncthreads();
    }
    #pragma unroll
    for (int a = 0; a < 4; ++a) {
        int bidx = ty * 4 + a;
        float4 o = {acc[a][0], acc[a][1], acc[a][2], acc[a][3]};
        *(float4*)(gpart + ((size_t)ky * B + bidx) * 1024 + cb * 64 + tx * 4) = o;
    }
}

// ---------------- batched head over all t: grid (157, 62) ----------------
__global__ __launch_bounds__(256) void head_batch(const float* __restrict__ hn_all,
                                                  const float* __restrict__ W_head,
                                                  const float* __restrict__ b_head,
                                                  const int* __restrict__ target,
                                                  float* __restrict__ out1) {
    int by = blockIdx.y;
    int t = by >> 1, qh = by & 1;
    if (target[qh * 32] <= t) return;   // sorted: whole 32-row tile inactive
    __shared__ float hs[32][260];
    int cb = blockIdx.x;
    int tid = threadIdx.x;
    #pragma unroll
    for (int q = 0; q < 8; ++q) {
        int idx = q * 256 + tid;
        int r = idx >> 6, kq = idx & 63;
        float4 v = *(const float4*)(hn_all + ((size_t)t * B + qh * 32 + r) * D + kq * 4);
        *(float4*)&hs[r][kq * 4] = v;
    }
    __syncthreads();
    int col = cb * 64 + (tid & 63);
    int rgrp = (tid >> 6) * 8;
    if (col < V) {
        float acc[8] = {};
        for (int kq = 0; kq < 64; ++kq) {
            float w0 = W_head[(size_t)(kq * 4 + 0) * V + col];
            float w1 = W_head[(size_t)(kq * 4 + 1) * V + col];
            float w2 = W_head[(size_t)(kq * 4 + 2) * V + col];
            float w3 = W_head[(size_t)(kq * 4 + 3) * V + col];
            #pragma unroll
            for (int r = 0; r < 8; ++r) {
                float4 hv = *(const float4*)&hs[rgrp + r][kq * 4];
                acc[r] += hv.x * w0 + hv.y * w1 + hv.z * w2 + hv.w * w3;
            }
        }
        float bh_ = b_head[col];
        #pragma unroll
        for (int r = 0; r < 8; ++r) {
            int brow = qh * 32 + rgrp + r;
            if (target[brow] > t)
                out1[((size_t)brow * T + t) * V + col] = acc[r] + bh_;
        }
    }
}

extern "C" void kernel_launch(void* const* d_in, const int* in_sizes, int n_in,
                              void* d_out, int out_size, void* d_ws, size_t ws_size,
                              hipStream_t stream) {
    const float* feat   = (const float*)d_in[0];
    const int*   tok    = (const int*)d_in[1];
    const int*   clen   = (const int*)d_in[2];
    const float* Wf     = (const float*)d_in[3];
    const float* bf     = (const float*)d_in[4];
    const float* Wh     = (const float*)d_in[5];
    const float* bh     = (const float*)d_in[6];
    const float* We     = (const float*)d_in[7];
    const float* be     = (const float*)d_in[8];
    const float* emb    = (const float*)d_in[9];
    const float* W_ih   = (const float*)d_in[10];
    const float* b_ih   = (const float*)d_in[11];
    const float* W_hh   = (const float*)d_in[12];
    const float* b_hh   = (const float*)d_in[13];
    const float* W_hid  = (const float*)d_in[14];
    const float* b_hid  = (const float*)d_in[15];
    const float* W_cell = (const float*)d_in[16];
    const float* b_cell = (const float*)d_in[17];
    const float* W_gate = (const float*)d_in[18];
    const float* b_gate = (const float*)d_in[19];
    const float* W_head = (const float*)d_in[20];
    const float* b_head = (const float*)d_in[21];

    float* out1 = (float*)d_out;
    float* out2 = out1 + (size_t)B * T * V;

    char* wp = (char*)d_ws;
    int* order   = (int*)wp;           wp += 256;
    int* targetp = (int*)wp;           wp += 256;
    float* fe    = (float*)wp;         wp += (size_t)B * P * H_ * sizeof(float);
    float* hbuf  = (float*)wp;         wp += (size_t)B * D * sizeof(float);
    float* cbuf  = (float*)wp;         wp += (size_t)B * D * sizeof(float);
    float* wbuf  = (float*)wp;         wp += (size_t)B * P * sizeof(float);
    float* xbuf  = (float*)wp;         wp += (size_t)B * KX * sizeof(float);
    float* gpart = (float*)wp;         wp += (size_t)8 * B * 1024 * sizeof(float);
    float* mean_feat = (float*)wp;     wp += (size_t)B * E * sizeof(float);
    float* hpart = (float*)wp;         wp += (size_t)8 * B * 512 * sizeof(float);
    float* hn_all = (float*)wp;        wp += (size_t)T * B * D * sizeof(float);

    hipMemsetAsync(d_out, 0, (size_t)out_size * sizeof(float), stream);

    sort_kernel<<<1, 64, 0, stream>>>(clen, order, targetp);
    mean_kernel<<<dim3(B, E / 256), 256, 0, stream>>>(feat, order, mean_feat);
    h0c0_gemm<<<dim3(8, 8), 256, 0, stream>>>(mean_feat, W_hid, W_cell, hpart);
    h0c0_reduce<<<B, 256, 0, stream>>>(hpart, b_hid, b_cell, emb, tok, order,
                                       hbuf, cbuf, xbuf);
    fe_gemm<<<dim3(196, 4), 256, 0, stream>>>(feat, order, Wf, bf, fe);

    for (int t = 0; t < T; ++t) {
        attn_pw<<<B, 256, 0, stream>>>(targetp, gpart, b_ih, b_hh, emb, tok, order,
                                       Wh, bh, We, be, fe, hbuf, cbuf, hn_all,
                                       xbuf, wbuf, out2, t);
        ctx_kernel<<<dim3(B, 8), 256, 0, stream>>>(feat, order, wbuf, W_gate, b_gate,
                                                   hbuf, targetp, xbuf, t);
        lstm_gemm<<<dim3(16, 8), 256, 0, stream>>>(xbuf, W_ih, W_hh, gpart);
    }
    attn_pw<<<B, 256, 0, stream>>>(targetp, gpart, b_ih, b_hh, emb, tok, order,
                                   Wh, bh, We, be, fe, hbuf, cbuf, hn_all,
                                   xbuf, wbuf, out2, T);
    head_batch<<<dim3(157, 62), 256, 0, stream>>>(hn_all, W_head, b_head, targetp, out1);
}